// Round 6
// baseline (389.673 us; speedup 1.0000x reference)
//
#include <hip/hip_runtime.h>
#include <hip/hip_cooperative_groups.h>
#include <hip/hip_bf16.h>
#include <stdint.h>

namespace cg = cooperative_groups;

#define D_MODEL 1024
#define NUM_EXPERTS 8
#define NBUCKET 16            // 8 primary + 8 secondary virtual experts
#define BM 128
#define BN 128
#define BK 64
#define KSTEPS (D_MODEL / BK)   // 16
#define GATE_TOK 16           // tokens per gate work (512 works)
#define GATE_WORKS 512        // T / GATE_TOK  (T = 8192)
#define NSEG (NUM_EXPERTS * KSTEPS * 1024 * 8)   // We 16B-segments: 1048576
#define GRID_MAX 512          // 2 blocks/CU (65 KiB LDS) x 256 CU

typedef __bf16 bf16x8 __attribute__((ext_vector_type(8)));
typedef float f32x4 __attribute__((ext_vector_type(4)));
typedef unsigned short u16x8 __attribute__((ext_vector_type(8)));

__device__ __forceinline__ unsigned short f32_to_bf16_rne(float f) {
    union { float f; uint32_t u; } v;
    v.f = f;
    uint32_t u = v.u;
    u += 0x7FFFu + ((u >> 16) & 1u);   // round-to-nearest-even
    return (unsigned short)(u >> 16);
}

__device__ __forceinline__ float bf16_to_f32(unsigned short h) {
    union { uint32_t u; float f; } v;
    v.u = ((uint32_t)h) << 16;
    return v.f;
}

__device__ __forceinline__ void gload_lds16(const unsigned short* g, unsigned short* l) {
    __builtin_amdgcn_global_load_lds(
        (const __attribute__((address_space(1))) void*)g,
        (__attribute__((address_space(3))) void*)l,
        16, 0, 0);
}

// ---------------------------------------------------------------------------
// ONE cooperative kernel: gate -> convert -> [grid.sync] -> gemm ->
// [grid.sync] -> combine. Launched via hipLaunchCooperativeKernel, which
// GUARANTEES all blocks co-resident (r4's manual-residency deadlock is
// structurally impossible: an oversized launch fails loudly instead).
// Phase bodies are the round-3 verified ones; every phase is a
// gridDim.x-stride loop so any granted grid size is correct.
// ---------------------------------------------------------------------------
__global__ __launch_bounds__(256, 2) void fused_moe(
    const float* __restrict__ x, const float* __restrict__ Wg,
    const float* __restrict__ bg, const float* __restrict__ We,
    const float* __restrict__ be, int T,
    int* __restrict__ counts,
    int* __restrict__ token_list, float* __restrict__ gate_list,
    unsigned short* __restrict__ xb, unsigned short* __restrict__ wbv,
    unsigned short* __restrict__ ybuf, float* __restrict__ out)
{
    cg::grid_group grid = cg::this_grid();

    const int tid  = threadIdx.x;
    const int bid  = blockIdx.x;
    const int lane = tid & 63;
    const int wave = tid >> 6;

    // LDS union (65 KiB -> 2 blocks/CU):
    //   gate view:  WgS 0..32767 | logitS 32768..33791 | cntS 33792 | baseS 33856
    //   gemm view:  As(2x16K) 0..32767 | Bs(2x16K) 32768..65535
    //               tokS 65536..66047 | gateS 66048..66559
    __shared__ __align__(16) unsigned char smem[66560];
    float4* WgS = (float4*)smem;
    double (*logitS)[NUM_EXPERTS] = (double (*)[NUM_EXPERTS])(smem + 32768);
    int* cntS  = (int*)(smem + 33792);
    int* baseS = (int*)(smem + 33856);
    unsigned short* AsB = (unsigned short*)smem;             // [2][BM*BK]
    unsigned short* BsB = (unsigned short*)(smem + 32768);   // [2][BN*BK]
    int*   tokS  = (int*)(smem + 65536);
    float* gateS = (float*)(smem + 66048);

    // ================= Phase A: gate =================
    // Stage Wg once per block (32 KB; L2-resident after first readers).
#pragma unroll
    for (int i = 0; i < 8; i++)
        WgS[i * 256 + tid] = ((const float4*)Wg)[i * 256 + tid];

    for (int w = bid; w < GATE_WORKS; w += gridDim.x) {
        __syncthreads();                    // Wg staged / prev work drained
        if (tid < NBUCKET) cntS[tid] = 0;
        __syncthreads();

        const int tokBase = w * GATE_TOK;
        // Each wave computes GATE_TOK/4 tokens' fp64 logits.
        for (int tt = 0; tt < GATE_TOK / 4; tt++) {
            const int lt = wave * (GATE_TOK / 4) + tt;
            const int token = tokBase + lt;
            const float4* xr4 = (const float4*)(x + (size_t)token * D_MODEL);
            ushort4* xbr4 = (ushort4*)(xb + (size_t)token * D_MODEL);

            float4 xv[4];
#pragma unroll
            for (int q = 0; q < 4; q++) {
                float4 f = xr4[q * 64 + lane];
                xv[q] = f;
                ushort4 o;
                o.x = f32_to_bf16_rne(f.x);
                o.y = f32_to_bf16_rne(f.y);
                o.z = f32_to_bf16_rne(f.z);
                o.w = f32_to_bf16_rne(f.w);
                xbr4[q * 64 + lane] = o;
            }

            double acc[NUM_EXPERTS];
#pragma unroll
            for (int e = 0; e < NUM_EXPERTS; e++) {
                double a = 0.0;
#pragma unroll
                for (int q = 0; q < 4; q++) {
                    float4 wv = WgS[e * 256 + q * 64 + lane];
                    a += (double)xv[q].x * (double)wv.x;
                    a += (double)xv[q].y * (double)wv.y;
                    a += (double)xv[q].z * (double)wv.z;
                    a += (double)xv[q].w * (double)wv.w;
                }
                acc[e] = a;
            }
#pragma unroll
            for (int e = 0; e < NUM_EXPERTS; e++) {
                double a = acc[e];
                for (int off = 32; off > 0; off >>= 1) a += __shfl_xor(a, off, 64);
                acc[e] = a;
            }
            if (lane == 0) {
#pragma unroll
                for (int e = 0; e < NUM_EXPERTS; e++)
                    logitS[lt][e] = acc[e] + (double)bg[e];
            }
        }
        __syncthreads();

        // One thread per token: strict top-2 (lower index wins ties, matches
        // lax.top_k) + fp64 softmax + block-aggregated bucket append.
        int i1 = 0, i2 = 0, o1 = 0, o2 = 0;
        double v1d = 0.0, v2d = 0.0;
        const int token2 = tokBase + tid;
        if (tid < GATE_TOK) {
            double lg[NUM_EXPERTS];
#pragma unroll
            for (int e = 0; e < NUM_EXPERTS; e++) lg[e] = logitS[tid][e];
            i1 = 0;
#pragma unroll
            for (int e = 1; e < NUM_EXPERTS; e++) if (lg[e] > lg[i1]) i1 = e;
            i2 = (i1 == 0) ? 1 : 0;
#pragma unroll
            for (int e = 0; e < NUM_EXPERTS; e++)
                if (e != i1 && lg[e] > lg[i2]) i2 = e;
            double m = lg[i1], den = 0.0;
#pragma unroll
            for (int e = 0; e < NUM_EXPERTS; e++) den += exp(lg[e] - m);
            v1d = exp(lg[i1] - m) / den;
            v2d = exp(lg[i2] - m) / den;
            o1 = atomicAdd(&cntS[i1], 1);          // primary bucket e
            o2 = atomicAdd(&cntS[8 + i2], 1);      // secondary bucket 8+e
        }
        __syncthreads();
        if (tid < NBUCKET) baseS[tid] = atomicAdd(&counts[tid], cntS[tid]);
        __syncthreads();
        if (tid < GATE_TOK) {
            int p1 = i1 * T + baseS[i1] + o1;
            token_list[p1] = token2;
            gate_list[p1]  = (float)v1d;
            int p2 = (8 + i2) * T + baseS[8 + i2] + o2;
            token_list[p2] = token2;
            gate_list[p2]  = (float)v2d;
        }
    }

    // ================= Phase B: We fp32 -> bf16 blocked+swizzled ==========
    //   wbv[e][kt][n][seg][8], stored seg = seg ^ (n & 7)
    for (int g = bid * 256 + tid; g < NSEG; g += gridDim.x * 256) {
        int s   = g & 7;
        int n   = (g >> 3) & 1023;
        int kt  = (g >> 13) & (KSTEPS - 1);
        int e   = g >> 17;

        const float* sp = We + ((size_t)(e * 1024 + n)) * 1024 + kt * BK + s * 8;
        float4 a = ((const float4*)sp)[0];
        float4 b = ((const float4*)sp)[1];
        u16x8 o;
        o[0] = f32_to_bf16_rne(a.x);
        o[1] = f32_to_bf16_rne(a.y);
        o[2] = f32_to_bf16_rne(a.z);
        o[3] = f32_to_bf16_rne(a.w);
        o[4] = f32_to_bf16_rne(b.x);
        o[5] = f32_to_bf16_rne(b.y);
        o[6] = f32_to_bf16_rne(b.z);
        o[7] = f32_to_bf16_rne(b.w);

        int ss = s ^ (n & 7);
        unsigned short* dp =
            wbv + (((size_t)(e * KSTEPS + kt) * 1024 + n) * BK) + ss * 8;
        *(u16x8*)dp = o;
    }

    __threadfence();
    grid.sync();               // gate lists + counts + xb + wbv visible
    __threadfence();

    // ================= Phase C: per-bucket gathered GEMM ==================
    // Round-3 verified body (counted-vmcnt double-buffer), in a work loop.
    const int nWork = ((T + BM - 1) / BM) * NBUCKET * 8;
    for (int work = bid; work < nWork; work += gridDim.x) {
        const int nt = work & 7;
        const int rest = work >> 3;
        const int vexp = rest & (NBUCKET - 1);
        const int mt = rest >> 4;
        const int e_w = vexp & 7;

        const int n_e = counts[vexp];
        const int m0 = mt * BM;
        if (m0 >= n_e) continue;            // block-uniform: barrier-safe
        const int n0 = nt * BN;

        __syncthreads();   // guard: prev work's epilogue reads of tokS/gateS

        if (tid < BM) {
            int r = m0 + tid;
            int tk = 0; float gv = 0.f;
            if (r < n_e) {
                tk = token_list[vexp * T + r];
                gv = gate_list[vexp * T + r];
            }
            tokS[tid]  = tk;
            gateS[tid] = gv;
        }
        __syncthreads();

        // A staging sources: per-token gather, XOR swizzle on the 16B segment
        // index applied on the SOURCE (LDS dest stays wave-linear).
        const unsigned short* asrc[4];
#pragma unroll
        for (int i = 0; i < 4; i++) {
            int flat = i * 256 + tid;
            int r = flat >> 3, seg = flat & 7;
            int ss = seg ^ (r & 7);
            asrc[i] = xb + (size_t)tokS[r] * D_MODEL + ss * 8;
        }
        const unsigned short* bsrc =
            wbv + (size_t)e_w * (KSTEPS * 1024 * BK) + (size_t)n0 * BK;

        const int wm = (wave >> 1) * 64, wn = (wave & 1) * 64;
        const int frow = lane & 15;
        const int qq = lane >> 4;
        const int sw8 = frow & 7;

        f32x4 acc[4][4];
#pragma unroll
        for (int mi = 0; mi < 4; mi++)
#pragma unroll
            for (int ni = 0; ni < 4; ni++)
                acc[mi][ni] = (f32x4){0.f, 0.f, 0.f, 0.f};

        // Prologue: stage K-tile 0 into buffer 0.
#pragma unroll
        for (int i = 0; i < 4; i++) {
            int flat = i * 256 + tid;
            gload_lds16(asrc[i], AsB + flat * 8);
            gload_lds16(bsrc + flat * 8, BsB + flat * 8);
        }

#pragma unroll 2
        for (int kt = 0; kt < KSTEPS; kt++) {
            const int cur = kt & 1;
            unsigned short* Ac = AsB + cur * (BM * BK);
            unsigned short* Bc = BsB + cur * (BN * BK);
            if (kt + 1 < KSTEPS) {
                unsigned short* An = AsB + (cur ^ 1) * (BM * BK);
                unsigned short* Bn = BsB + (cur ^ 1) * (BN * BK);
#pragma unroll
                for (int i = 0; i < 4; i++) {
                    int flat = i * 256 + tid;
                    gload_lds16(asrc[i] + (kt + 1) * BK, An + flat * 8);
                    gload_lds16(bsrc + (size_t)(kt + 1) * (1024 * BK) + flat * 8,
                                Bn + flat * 8);
                }
                asm volatile("s_waitcnt vmcnt(8)" ::: "memory");  // tile k done
            } else {
                asm volatile("s_waitcnt vmcnt(0)" ::: "memory");  // tail
            }
            __builtin_amdgcn_sched_barrier(0);
            __builtin_amdgcn_s_barrier();          // all waves: tile k in LDS
            __builtin_amdgcn_sched_barrier(0);

#pragma unroll
            for (int ks = 0; ks < 2; ks++) {
                const int off = ((ks * 4 + qq) ^ sw8) * 8;   // swizzled k-off
                bf16x8 af[4], bfv[4];
#pragma unroll
                for (int mi = 0; mi < 4; mi++)
                    af[mi] = *(const bf16x8*)&Ac[(wm + mi * 16 + frow) * BK + off];
#pragma unroll
                for (int ni = 0; ni < 4; ni++)
                    bfv[ni] = *(const bf16x8*)&Bc[(wn + ni * 16 + frow) * BK + off];
#pragma unroll
                for (int mi = 0; mi < 4; mi++)
#pragma unroll
                    for (int ni = 0; ni < 4; ni++)
                        acc[mi][ni] = __builtin_amdgcn_mfma_f32_16x16x32_bf16(
                            af[mi], bfv[ni], acc[mi][ni], 0, 0, 0);
            }
            __builtin_amdgcn_sched_barrier(0);
            __builtin_amdgcn_s_barrier();          // buf[cur] free for k+2
            __builtin_amdgcn_sched_barrier(0);
        }

        // Epilogue: C/D layout col = lane&15, row = (lane>>4)*4 + reg.
        unsigned short* ybase = ybuf + (size_t)(vexp >> 3) * T * D_MODEL;
        const int rbase = (lane >> 4) * 4;
        const int col   = lane & 15;
#pragma unroll
        for (int mi = 0; mi < 4; mi++) {
#pragma unroll
            for (int r = 0; r < 4; r++) {
                int lrow = wm + mi * 16 + rbase + r;
                if (m0 + lrow < n_e) {
                    int   tk = tokS[lrow];
                    float gv = gateS[lrow];
                    unsigned short* yr = ybase + (size_t)tk * D_MODEL;
#pragma unroll
                    for (int ni = 0; ni < 4; ni++) {
                        int c = n0 + wn + ni * 16 + col;
                        float val = gv * (acc[mi][ni][r] + be[e_w * D_MODEL + c]);
                        yr[c] = f32_to_bf16_rne(val);
                    }
                }
            }
        }
    }

    __threadfence();
    grid.sync();               // all ybuf writes visible
    __threadfence();

    // ================= Phase D: combine =================
    const unsigned short* y0 = ybuf;
    const unsigned short* y1 = ybuf + (size_t)T * D_MODEL;
    const int n4c = T * D_MODEL / 4;
    for (int i = bid * 256 + tid; i < n4c; i += gridDim.x * 256) {
        ushort4 a = ((const ushort4*)y0)[i];
        ushort4 b = ((const ushort4*)y1)[i];
        float4 o;
        o.x = bf16_to_f32(a.x) + bf16_to_f32(b.x);
        o.y = bf16_to_f32(a.y) + bf16_to_f32(b.y);
        o.z = bf16_to_f32(a.z) + bf16_to_f32(b.z);
        o.w = bf16_to_f32(a.w) + bf16_to_f32(b.w);
        ((float4*)out)[i] = o;
    }
}

extern "C" void kernel_launch(void* const* d_in, const int* in_sizes, int n_in,
                              void* d_out, int out_size, void* d_ws, size_t ws_size,
                              hipStream_t stream) {
    const float* x  = (const float*)d_in[0];
    const float* Wg = (const float*)d_in[1];
    const float* bg = (const float*)d_in[2];
    const float* We = (const float*)d_in[3];
    const float* be = (const float*)d_in[4];
    // top_k (d_in[5]) is fixed at 2 per the reference; hard-coded.

    int T = in_sizes[0] / D_MODEL;   // 8192 tokens

    // workspace carve-up (~68 MB total)
    char* ws = (char*)d_ws;
    unsigned short* xb = (unsigned short*)ws;                       // T*D bf16
    size_t off = (size_t)T * D_MODEL * 2;
    unsigned short* wbv = (unsigned short*)(ws + off);              // E*D*D bf16
    off += (size_t)NUM_EXPERTS * D_MODEL * D_MODEL * 2;
    int* counts = (int*)(ws + off);         off += 256;
    int* token_list = (int*)(ws + off);     off += (size_t)NBUCKET * T * 4;
    float* gate_list = (float*)(ws + off);  off += (size_t)NBUCKET * T * 4;
    unsigned short* ybuf = (unsigned short*)(ws + off);             // 2*T*D bf16
    off += (size_t)2 * T * D_MODEL * 2;
    float* outp = (float*)d_out;

    // Cooperative grid size: runtime-validated occupancy (no manual capacity
    // arithmetic — the r4 lesson). 65 KiB LDS -> expect 2 blocks/CU -> 512.
    static int s_grid = 0;
    if (s_grid == 0) {
        int nb = 0;
        if (hipOccupancyMaxActiveBlocksPerMultiprocessor(&nb, fused_moe, 256, 0)
                != hipSuccess || nb < 1)
            nb = 1;
        int g = nb * 256;                    // 256 CUs on MI355X
        s_grid = g < GRID_MAX ? g : GRID_MAX;
    }

    hipMemsetAsync(counts, 0, 256, stream);

    void* kargs[] = {
        (void*)&x, (void*)&Wg, (void*)&bg, (void*)&We, (void*)&be, (void*)&T,
        (void*)&counts, (void*)&token_list, (void*)&gate_list,
        (void*)&xb, (void*)&wbv, (void*)&ybuf, (void*)&outp
    };
    hipLaunchCooperativeKernel((const void*)fused_moe, dim3(s_grid), dim3(256),
                               kargs, 0, stream);
}

// Round 7
// 305.790 us; speedup vs baseline: 1.2743x; 1.2743x over previous
//
#include <hip/hip_runtime.h>
#include <hip/hip_bf16.h>
#include <stdint.h>

#define D_MODEL 1024
#define NUM_EXPERTS 8
#define NBUCKET 16            // 8 primary + 8 secondary virtual experts
#define BM 128
#define BN 128
#define BK 64
#define KSTEPS (D_MODEL / BK)   // 16
#define GATE_TOK 32           // tokens per gate block (256 blocks, 512 thr)

typedef __bf16 bf16x8 __attribute__((ext_vector_type(8)));
typedef float f32x4 __attribute__((ext_vector_type(4)));
typedef unsigned short u16x8 __attribute__((ext_vector_type(8)));

__device__ __forceinline__ unsigned short f32_to_bf16_rne(float f) {
    union { float f; uint32_t u; } v;
    v.f = f;
    uint32_t u = v.u;
    u += 0x7FFFu + ((u >> 16) & 1u);   // round-to-nearest-even
    return (unsigned short)(u >> 16);
}

__device__ __forceinline__ void gload_lds16(const unsigned short* g, unsigned short* l) {
    __builtin_amdgcn_global_load_lds(
        (const __attribute__((address_space(1))) void*)g,
        (__attribute__((address_space(3))) void*)l,
        16, 0, 0);
}

// ---------------------------------------------------------------------------
// Gate kernel: same 256 blocks / 32 KB-Wg-staging economics as the verified
// r3 version (r5 proved staging scales with block count), but 512 threads:
// 8 waves/CU instead of 4 to hide the fp64 shuffle-reduce and load latency.
// fp64 logits -> strict top-2 (lower index wins ties, matches lax.top_k),
// fp64 softmax, 16-bucket aggregated append; fuses x fp32->bf16 (RNE).
// ---------------------------------------------------------------------------
__global__ __launch_bounds__(512) void gate_kernel(
    const float* __restrict__ x, const float* __restrict__ Wg,
    const float* __restrict__ bg, int T,
    int* __restrict__ counts, int* __restrict__ token_list,
    float* __restrict__ gate_list, unsigned short* __restrict__ xb)
{
    const int tid  = threadIdx.x;
    const int lane = tid & 63;
    const int wave = tid >> 6;            // 0..7
    const int tokBase = blockIdx.x * GATE_TOK;

    __shared__ float4 WgS[NUM_EXPERTS * 256];   // 32 KB
    __shared__ double logitS[GATE_TOK][NUM_EXPERTS];
    __shared__ int cntS[NBUCKET];
    __shared__ int baseS[NBUCKET];

    if (tid < NBUCKET) cntS[tid] = 0;
#pragma unroll
    for (int i = 0; i < 4; i++)
        WgS[i * 512 + tid] = ((const float4*)Wg)[i * 512 + tid];
    __syncthreads();

    // Each of 8 waves handles GATE_TOK/8 = 4 tokens.
    for (int tt = 0; tt < GATE_TOK / 8; tt++) {
        const int lt = wave * (GATE_TOK / 8) + tt;
        const int token = tokBase + lt;
        const float4* xr4 = (const float4*)(x + (size_t)token * D_MODEL);
        ushort4* xbr4 = (ushort4*)(xb + (size_t)token * D_MODEL);

        float4 xv[4];
#pragma unroll
        for (int q = 0; q < 4; q++) {
            float4 f = xr4[q * 64 + lane];
            xv[q] = f;
            ushort4 o;
            o.x = f32_to_bf16_rne(f.x);
            o.y = f32_to_bf16_rne(f.y);
            o.z = f32_to_bf16_rne(f.z);
            o.w = f32_to_bf16_rne(f.w);
            xbr4[q * 64 + lane] = o;
        }

        double acc[NUM_EXPERTS];
#pragma unroll
        for (int e = 0; e < NUM_EXPERTS; e++) {
            double a = 0.0;
#pragma unroll
            for (int q = 0; q < 4; q++) {
                float4 w = WgS[e * 256 + q * 64 + lane];
                a += (double)xv[q].x * (double)w.x;
                a += (double)xv[q].y * (double)w.y;
                a += (double)xv[q].z * (double)w.z;
                a += (double)xv[q].w * (double)w.w;
            }
            acc[e] = a;
        }
#pragma unroll
        for (int e = 0; e < NUM_EXPERTS; e++) {
            double a = acc[e];
            for (int off = 32; off > 0; off >>= 1) a += __shfl_xor(a, off, 64);
            acc[e] = a;
        }
        if (lane == 0) {
#pragma unroll
            for (int e = 0; e < NUM_EXPERTS; e++)
                logitS[lt][e] = acc[e] + (double)bg[e];
        }
    }
    __syncthreads();

    int i1 = 0, i2 = 0, o1 = 0, o2 = 0;
    double v1d = 0.0, v2d = 0.0;
    const int token2 = tokBase + tid;
    if (tid < GATE_TOK) {
        double lg[NUM_EXPERTS];
#pragma unroll
        for (int e = 0; e < NUM_EXPERTS; e++) lg[e] = logitS[tid][e];
        i1 = 0;
#pragma unroll
        for (int e = 1; e < NUM_EXPERTS; e++) if (lg[e] > lg[i1]) i1 = e;
        i2 = (i1 == 0) ? 1 : 0;
#pragma unroll
        for (int e = 0; e < NUM_EXPERTS; e++)
            if (e != i1 && lg[e] > lg[i2]) i2 = e;
        double m = lg[i1], den = 0.0;
#pragma unroll
        for (int e = 0; e < NUM_EXPERTS; e++) den += exp(lg[e] - m);
        v1d = exp(lg[i1] - m) / den;
        v2d = exp(lg[i2] - m) / den;
        o1 = atomicAdd(&cntS[i1], 1);          // primary bucket e
        o2 = atomicAdd(&cntS[8 + i2], 1);      // secondary bucket 8+e
    }
    __syncthreads();
    if (tid < NBUCKET) baseS[tid] = atomicAdd(&counts[tid], cntS[tid]);
    __syncthreads();
    if (tid < GATE_TOK) {
        int p1 = i1 * T + baseS[i1] + o1;
        token_list[p1] = token2;
        gate_list[p1]  = (float)v1d;
        int p2 = (8 + i2) * T + baseS[8 + i2] + o2;
        token_list[p2] = token2;
        gate_list[p2]  = (float)v2d;
    }
}

// ---------------------------------------------------------------------------
// fp32 -> bf16 converter for We (r3 version, unchanged). Output layout:
//   wbv[e][kt][n][seg][8] with stored seg = seg ^ (n & 7)  (pre-swizzled).
// ---------------------------------------------------------------------------
__global__ __launch_bounds__(256) void convert_kernel(
    const float* __restrict__ src, unsigned short* __restrict__ dst)
{
    int gid = blockIdx.x * 256 + threadIdx.x;   // 0 .. E*16*1024*8 - 1
    int s   = gid & 7;
    int n   = (gid >> 3) & 1023;
    int kt  = (gid >> 13) & (KSTEPS - 1);
    int e   = gid >> 17;

    const float* sp = src + ((size_t)(e * 1024 + n)) * 1024 + kt * BK + s * 8;
    float4 a = ((const float4*)sp)[0];
    float4 b = ((const float4*)sp)[1];
    u16x8 o;
    o[0] = f32_to_bf16_rne(a.x);
    o[1] = f32_to_bf16_rne(a.y);
    o[2] = f32_to_bf16_rne(a.z);
    o[3] = f32_to_bf16_rne(a.w);
    o[4] = f32_to_bf16_rne(b.x);
    o[5] = f32_to_bf16_rne(b.y);
    o[6] = f32_to_bf16_rne(b.z);
    o[7] = f32_to_bf16_rne(b.w);

    int ss = s ^ (n & 7);
    unsigned short* dp = dst + (((size_t)(e * KSTEPS + kt) * 1024 + n) * BK) + ss * 8;
    *(u16x8*)dp = o;
}

// ---------------------------------------------------------------------------
// Per-bucket gathered GEMM (r3-verified counted-vmcnt K-loop, unchanged).
// NEW: two dispatches replace gemm+combine.
//   sec=0: buckets 0..7  (primary)   -> out[t][c]  = gv*(Wx+b)   (fp32 store)
//   sec=1: buckets 8..15 (secondary) -> out[t][c] += gv*(Wx+b)   (race-free
//          RMW: within a bucket class each token appears exactly once, and
//          gemm1->gemm2 ordering + visibility come from the dispatch
//          boundary's device-scope release -- no atomics needed).
// ---------------------------------------------------------------------------
__global__ __launch_bounds__(256) void moe_gemm(
    const unsigned short* __restrict__ xb,   // [T][1024] bf16
    const unsigned short* __restrict__ wb,   // [E][16][1024][64] bf16, swizzled
    const float* __restrict__ be,            // [E][1024]
    const int* __restrict__ counts,          // [16]
    const int* __restrict__ token_list,      // [16][T]
    const float* __restrict__ gate_list,     // [16][T]
    float* out,                              // [T][1024] fp32 (no restrict: RMW)
    int T, int sec)
{
    const int bid = blockIdx.x;
    const int nt = bid & 7;                 // low 3 bits: XCD-aligned B panels
    const int rest = bid >> 3;
    const int vloc = rest & 7;
    const int mt = rest >> 3;
    const int vexp = sec * 8 + vloc;
    const int e_w = vloc;

    const int n_e = counts[vexp];
    const int m0 = mt * BM;
    if (m0 >= n_e) return;
    const int n0 = nt * BN;
    const int tid = threadIdx.x;

    __shared__ __align__(16) unsigned short As[2][BM * BK];   // 2 x 16 KB
    __shared__ __align__(16) unsigned short Bs[2][BN * BK];   // 2 x 16 KB
    __shared__ int   tokS[BM];
    __shared__ float gateS[BM];

    if (tid < BM) {
        int r = m0 + tid;
        int tk = 0; float gv = 0.f;
        if (r < n_e) {
            tk = token_list[vexp * T + r];
            gv = gate_list[vexp * T + r];
        }
        tokS[tid]  = tk;
        gateS[tid] = gv;
    }
    __syncthreads();

    // A staging sources: per-token gather, XOR swizzle on the 16B segment
    // index applied on the SOURCE (LDS dest stays wave-linear).
    const unsigned short* asrc[4];
#pragma unroll
    for (int i = 0; i < 4; i++) {
        int flat = i * 256 + tid;
        int r = flat >> 3, seg = flat & 7;
        int ss = seg ^ (r & 7);
        asrc[i] = xb + (size_t)tokS[r] * D_MODEL + ss * 8;
    }
    // B staging source: fully linear within each 16 KB per-K-step tile.
    const unsigned short* bsrc =
        wb + (size_t)e_w * (KSTEPS * 1024 * BK) + (size_t)n0 * BK;

    const int wave = tid >> 6, lane = tid & 63;
    const int wm = (wave >> 1) * 64, wn = (wave & 1) * 64;
    const int frow = lane & 15;
    const int qq = lane >> 4;
    const int sw8 = frow & 7;

    f32x4 acc[4][4];
#pragma unroll
    for (int mi = 0; mi < 4; mi++)
#pragma unroll
        for (int ni = 0; ni < 4; ni++)
            acc[mi][ni] = (f32x4){0.f, 0.f, 0.f, 0.f};

    // Prologue: stage K-tile 0 into buffer 0 (8 vm ops; waited in-loop).
#pragma unroll
    for (int i = 0; i < 4; i++) {
        int flat = i * 256 + tid;
        gload_lds16(asrc[i], &As[0][flat * 8]);
        gload_lds16(bsrc + flat * 8, &Bs[0][flat * 8]);
    }

#pragma unroll 2
    for (int kt = 0; kt < KSTEPS; kt++) {
        const int cur = kt & 1;
        // Prefetch next K-tile into the other buffer; its loads stay in
        // flight across both barriers (counted wait below, never vmcnt(0)).
        if (kt + 1 < KSTEPS) {
#pragma unroll
            for (int i = 0; i < 4; i++) {
                int flat = i * 256 + tid;
                gload_lds16(asrc[i] + (kt + 1) * BK, &As[cur ^ 1][flat * 8]);
                gload_lds16(bsrc + (size_t)(kt + 1) * (1024 * BK) + flat * 8,
                            &Bs[cur ^ 1][flat * 8]);
            }
            asm volatile("s_waitcnt vmcnt(8)" ::: "memory");  // tile k done
        } else {
            asm volatile("s_waitcnt vmcnt(0)" ::: "memory");  // tail
        }
        __builtin_amdgcn_sched_barrier(0);
        __builtin_amdgcn_s_barrier();          // all waves: tile k in LDS
        __builtin_amdgcn_sched_barrier(0);

#pragma unroll
        for (int ks = 0; ks < 2; ks++) {
            const int off = ((ks * 4 + qq) ^ sw8) * 8;   // swizzled k-offset
            bf16x8 af[4], bfv[4];
#pragma unroll
            for (int mi = 0; mi < 4; mi++)
                af[mi] = *(const bf16x8*)&As[cur][(wm + mi * 16 + frow) * BK + off];
#pragma unroll
            for (int ni = 0; ni < 4; ni++)
                bfv[ni] = *(const bf16x8*)&Bs[cur][(wn + ni * 16 + frow) * BK + off];
#pragma unroll
            for (int mi = 0; mi < 4; mi++)
#pragma unroll
                for (int ni = 0; ni < 4; ni++)
                    acc[mi][ni] = __builtin_amdgcn_mfma_f32_16x16x32_bf16(
                        af[mi], bfv[ni], acc[mi][ni], 0, 0, 0);
        }
        __builtin_amdgcn_sched_barrier(0);
        __builtin_amdgcn_s_barrier();          // buf[cur] free for stage(k+2)
        __builtin_amdgcn_sched_barrier(0);
    }

    // Epilogue: C/D layout col = lane&15, row = (lane>>4)*4 + reg.
    // fp32 stores to out; sec=1 adds the already-written primary value.
    const int rbase = (lane >> 4) * 4;
    const int col   = lane & 15;
#pragma unroll
    for (int mi = 0; mi < 4; mi++) {
#pragma unroll
        for (int r = 0; r < 4; r++) {
            int lrow = wm + mi * 16 + rbase + r;
            if (m0 + lrow < n_e) {
                int   tk = tokS[lrow];
                float gv = gateS[lrow];
                float* yr = out + (size_t)tk * D_MODEL;
#pragma unroll
                for (int ni = 0; ni < 4; ni++) {
                    int c = n0 + wn + ni * 16 + col;
                    float val = gv * (acc[mi][ni][r] + be[e_w * D_MODEL + c]);
                    if (sec) val += yr[c];
                    yr[c] = val;
                }
            }
        }
    }
}

extern "C" void kernel_launch(void* const* d_in, const int* in_sizes, int n_in,
                              void* d_out, int out_size, void* d_ws, size_t ws_size,
                              hipStream_t stream) {
    const float* x  = (const float*)d_in[0];
    const float* Wg = (const float*)d_in[1];
    const float* bg = (const float*)d_in[2];
    const float* We = (const float*)d_in[3];
    const float* be = (const float*)d_in[4];
    // top_k (d_in[5]) is fixed at 2 per the reference; hard-coded.

    const int T = in_sizes[0] / D_MODEL;   // 8192 tokens

    // workspace carve-up
    char* ws = (char*)d_ws;
    unsigned short* xb = (unsigned short*)ws;                       // T*D bf16
    size_t off = (size_t)T * D_MODEL * 2;
    unsigned short* wbv = (unsigned short*)(ws + off);              // E*D*D bf16
    off += (size_t)NUM_EXPERTS * D_MODEL * D_MODEL * 2;
    int* counts = (int*)(ws + off);         off += 256;
    int* token_list = (int*)(ws + off);     off += (size_t)NBUCKET * T * 4;
    float* gate_list = (float*)(ws + off);  off += (size_t)NBUCKET * T * 4;

    hipMemsetAsync(counts, 0, 256, stream);

    int nseg = NUM_EXPERTS * KSTEPS * 1024 * 8;   // one thread per 16B segment
    convert_kernel<<<nseg / 256, 256, 0, stream>>>(We, wbv);

    gate_kernel<<<T / GATE_TOK, 512, 0, stream>>>(
        x, Wg, bg, T, counts, token_list, gate_list, xb);

    const int MT = (T + BM - 1) / BM;       // worst case: all tokens in one class
    // primary class writes out; secondary class read-modify-writes (ordered
    // and made visible by the dispatch boundary's device-scope release).
    moe_gemm<<<MT * 8 * 8, 256, 0, stream>>>(
        xb, wbv, be, counts, token_list, gate_list, (float*)d_out, T, 0);
    moe_gemm<<<MT * 8 * 8, 256, 0, stream>>>(
        xb, wbv, be, counts, token_list, gate_list, (float*)d_out, T, 1);
}

// Round 8
// 263.683 us; speedup vs baseline: 1.4778x; 1.1597x over previous
//
#include <hip/hip_runtime.h>
#include <hip/hip_bf16.h>
#include <stdint.h>

#define D_MODEL 1024
#define NUM_EXPERTS 8
#define NBUCKET 16            // 8 primary + 8 secondary virtual experts
#define BM 128
#define BN 128
#define BK 64
#define KSTEPS (D_MODEL / BK)   // 16
#define GATE_TOK 32           // tokens per gate block (256 blocks, 512 thr)

typedef __bf16 bf16x8 __attribute__((ext_vector_type(8)));
typedef float f32x4 __attribute__((ext_vector_type(4)));
typedef unsigned short u16x8 __attribute__((ext_vector_type(8)));

__device__ __forceinline__ unsigned short f32_to_bf16_rne(float f) {
    union { float f; uint32_t u; } v;
    v.f = f;
    uint32_t u = v.u;
    u += 0x7FFFu + ((u >> 16) & 1u);   // round-to-nearest-even
    return (unsigned short)(u >> 16);
}

__device__ __forceinline__ float bf16_to_f32(unsigned short h) {
    union { uint32_t u; float f; } v;
    v.u = ((uint32_t)h) << 16;
    return v.f;
}

__device__ __forceinline__ void gload_lds16(const unsigned short* g, unsigned short* l) {
    __builtin_amdgcn_global_load_lds(
        (const __attribute__((address_space(1))) void*)g,
        (__attribute__((address_space(3))) void*)l,
        16, 0, 0);
}

// ---------------------------------------------------------------------------
// Gate kernel (r7-verified, 256 blocks x 512 threads): Wg staged in LDS,
// fp64 logits -> strict top-2 (lower index wins ties, matches lax.top_k),
// fp64 softmax, 16-bucket aggregated append; fuses x fp32->bf16 (RNE).
// ---------------------------------------------------------------------------
__global__ __launch_bounds__(512) void gate_kernel(
    const float* __restrict__ x, const float* __restrict__ Wg,
    const float* __restrict__ bg, int T,
    int* __restrict__ counts, int* __restrict__ token_list,
    float* __restrict__ gate_list, unsigned short* __restrict__ xb)
{
    const int tid  = threadIdx.x;
    const int lane = tid & 63;
    const int wave = tid >> 6;            // 0..7
    const int tokBase = blockIdx.x * GATE_TOK;

    __shared__ float4 WgS[NUM_EXPERTS * 256];   // 32 KB
    __shared__ double logitS[GATE_TOK][NUM_EXPERTS];
    __shared__ int cntS[NBUCKET];
    __shared__ int baseS[NBUCKET];

    if (tid < NBUCKET) cntS[tid] = 0;
#pragma unroll
    for (int i = 0; i < 4; i++)
        WgS[i * 512 + tid] = ((const float4*)Wg)[i * 512 + tid];
    __syncthreads();

    // Each of 8 waves handles GATE_TOK/8 = 4 tokens.
    for (int tt = 0; tt < GATE_TOK / 8; tt++) {
        const int lt = wave * (GATE_TOK / 8) + tt;
        const int token = tokBase + lt;
        const float4* xr4 = (const float4*)(x + (size_t)token * D_MODEL);
        ushort4* xbr4 = (ushort4*)(xb + (size_t)token * D_MODEL);

        float4 xv[4];
#pragma unroll
        for (int q = 0; q < 4; q++) {
            float4 f = xr4[q * 64 + lane];
            xv[q] = f;
            ushort4 o;
            o.x = f32_to_bf16_rne(f.x);
            o.y = f32_to_bf16_rne(f.y);
            o.z = f32_to_bf16_rne(f.z);
            o.w = f32_to_bf16_rne(f.w);
            xbr4[q * 64 + lane] = o;
        }

        double acc[NUM_EXPERTS];
#pragma unroll
        for (int e = 0; e < NUM_EXPERTS; e++) {
            double a = 0.0;
#pragma unroll
            for (int q = 0; q < 4; q++) {
                float4 w = WgS[e * 256 + q * 64 + lane];
                a += (double)xv[q].x * (double)w.x;
                a += (double)xv[q].y * (double)w.y;
                a += (double)xv[q].z * (double)w.z;
                a += (double)xv[q].w * (double)w.w;
            }
            acc[e] = a;
        }
#pragma unroll
        for (int e = 0; e < NUM_EXPERTS; e++) {
            double a = acc[e];
            for (int off = 32; off > 0; off >>= 1) a += __shfl_xor(a, off, 64);
            acc[e] = a;
        }
        if (lane == 0) {
#pragma unroll
            for (int e = 0; e < NUM_EXPERTS; e++)
                logitS[lt][e] = acc[e] + (double)bg[e];
        }
    }
    __syncthreads();

    int i1 = 0, i2 = 0, o1 = 0, o2 = 0;
    double v1d = 0.0, v2d = 0.0;
    const int token2 = tokBase + tid;
    if (tid < GATE_TOK) {
        double lg[NUM_EXPERTS];
#pragma unroll
        for (int e = 0; e < NUM_EXPERTS; e++) lg[e] = logitS[tid][e];
        i1 = 0;
#pragma unroll
        for (int e = 1; e < NUM_EXPERTS; e++) if (lg[e] > lg[i1]) i1 = e;
        i2 = (i1 == 0) ? 1 : 0;
#pragma unroll
        for (int e = 0; e < NUM_EXPERTS; e++)
            if (e != i1 && lg[e] > lg[i2]) i2 = e;
        double m = lg[i1], den = 0.0;
#pragma unroll
        for (int e = 0; e < NUM_EXPERTS; e++) den += exp(lg[e] - m);
        v1d = exp(lg[i1] - m) / den;
        v2d = exp(lg[i2] - m) / den;
        o1 = atomicAdd(&cntS[i1], 1);          // primary bucket e
        o2 = atomicAdd(&cntS[8 + i2], 1);      // secondary bucket 8+e
    }
    __syncthreads();
    if (tid < NBUCKET) baseS[tid] = atomicAdd(&counts[tid], cntS[tid]);
    __syncthreads();
    if (tid < GATE_TOK) {
        int p1 = i1 * T + baseS[i1] + o1;
        token_list[p1] = token2;
        gate_list[p1]  = (float)v1d;
        int p2 = (8 + i2) * T + baseS[8 + i2] + o2;
        token_list[p2] = token2;
        gate_list[p2]  = (float)v2d;
    }
}

// ---------------------------------------------------------------------------
// Per-bucket gathered GEMM with FUSED We fp32->bf16 conversion (convert
// kernel deleted). A-side: unchanged gload_lds gather from xb (bf16, source
// XOR-swizzle). B-side: reg-staged from We fp32 (T14 split):
//   issue B(k+1) float4 loads + A(k+1) gload_lds  [pinned before compute]
//   compute(k)                                      [covers the load latency]
//   cvt B(k+1) -> bf16, ds_write_b128 to the SAME swizzled LDS slots the old
//   pre-swizzled wbv staging produced (byte-identical image; read path and
//   MFMA loop untouched)
//   __syncthreads()                                 [one barrier per K-step]
// ---------------------------------------------------------------------------
__global__ __launch_bounds__(256) void moe_gemm(
    const unsigned short* __restrict__ xb,   // [T][1024] bf16
    const float* __restrict__ We,            // [E][1024][1024] fp32, K-contig
    const float* __restrict__ be,            // [E][1024]
    const int* __restrict__ counts,          // [16]
    const int* __restrict__ token_list,      // [16][T]
    const float* __restrict__ gate_list,     // [16][T]
    unsigned short* __restrict__ ybuf,       // [2][T][1024] bf16
    int T)
{
    const int bid = blockIdx.x;
    const int nt = bid & 7;
    const int rest = bid >> 3;
    const int vexp = rest & (NBUCKET - 1);
    const int mt = rest >> 4;
    const int e_w = vexp & 7;

    const int n_e = counts[vexp];
    const int m0 = mt * BM;
    if (m0 >= n_e) return;
    const int n0 = nt * BN;
    const int tid = threadIdx.x;

    __shared__ __align__(16) unsigned short As[2][BM * BK];   // 2 x 16 KB
    __shared__ __align__(16) unsigned short Bs[2][BN * BK];   // 2 x 16 KB
    __shared__ int   tokS[BM];
    __shared__ float gateS[BM];

    if (tid < BM) {
        int r = m0 + tid;
        int tk = 0; float gv = 0.f;
        if (r < n_e) {
            tk = token_list[vexp * T + r];
            gv = gate_list[vexp * T + r];
        }
        tokS[tid]  = tk;
        gateS[tid] = gv;
    }
    __syncthreads();

    // A staging sources: per-token gather, XOR swizzle on the 16B segment
    // index applied on the SOURCE (LDS dest stays wave-linear).
    // B staging sources: direct fp32 We rows; swizzle applied on the
    // ds_write DESTINATION (reg-staging allows it).
    const unsigned short* asrc[4];
    const float* wsrc[4];
    int bdst[4];
#pragma unroll
    for (int i = 0; i < 4; i++) {
        int flat = i * 256 + tid;
        int r = flat >> 3, seg = flat & 7;
        int ss = seg ^ (r & 7);
        asrc[i] = xb + (size_t)tokS[r] * D_MODEL + ss * 8;
        wsrc[i] = We + (size_t)e_w * (D_MODEL * D_MODEL)
                     + (size_t)(n0 + r) * D_MODEL + seg * 8;
        bdst[i] = r * BK + ss * 8;             // half-index into Bs
    }

    const int wave = tid >> 6, lane = tid & 63;
    const int wm = (wave >> 1) * 64, wn = (wave & 1) * 64;
    const int frow = lane & 15;
    const int qq = lane >> 4;
    const int sw8 = frow & 7;

    f32x4 acc[4][4];
#pragma unroll
    for (int mi = 0; mi < 4; mi++)
#pragma unroll
        for (int ni = 0; ni < 4; ni++)
            acc[mi][ni] = (f32x4){0.f, 0.f, 0.f, 0.f};

    // Prologue: stage K-tile 0 (A via gload_lds; B via reg->cvt->ds_write).
    float4 p0[4], p1[4];
#pragma unroll
    for (int i = 0; i < 4; i++) {
        p0[i] = ((const float4*)wsrc[i])[0];
        p1[i] = ((const float4*)wsrc[i])[1];
        int flat = i * 256 + tid;
        gload_lds16(asrc[i], &As[0][flat * 8]);
    }
#pragma unroll
    for (int i = 0; i < 4; i++) {
        u16x8 h;
        h[0] = f32_to_bf16_rne(p0[i].x);
        h[1] = f32_to_bf16_rne(p0[i].y);
        h[2] = f32_to_bf16_rne(p0[i].z);
        h[3] = f32_to_bf16_rne(p0[i].w);
        h[4] = f32_to_bf16_rne(p1[i].x);
        h[5] = f32_to_bf16_rne(p1[i].y);
        h[6] = f32_to_bf16_rne(p1[i].z);
        h[7] = f32_to_bf16_rne(p1[i].w);
        *(u16x8*)&Bs[0][bdst[i]] = h;
    }
    __syncthreads();

#pragma unroll 2
    for (int kt = 0; kt < KSTEPS; kt++) {
        const int cur = kt & 1;
        // Issue next tile's loads BEFORE compute (sched_barrier pins them).
        if (kt + 1 < KSTEPS) {
#pragma unroll
            for (int i = 0; i < 4; i++) {
                const float* wp = wsrc[i] + (kt + 1) * BK;
                p0[i] = ((const float4*)wp)[0];
                p1[i] = ((const float4*)wp)[1];
                int flat = i * 256 + tid;
                gload_lds16(asrc[i] + (kt + 1) * BK, &As[cur ^ 1][flat * 8]);
            }
        }
        __builtin_amdgcn_sched_barrier(0);

        // Compute tile k (read path identical to the verified r3 kernel).
#pragma unroll
        for (int ks = 0; ks < 2; ks++) {
            const int off = ((ks * 4 + qq) ^ sw8) * 8;   // swizzled k-offset
            bf16x8 af[4], bfv[4];
#pragma unroll
            for (int mi = 0; mi < 4; mi++)
                af[mi] = *(const bf16x8*)&As[cur][(wm + mi * 16 + frow) * BK + off];
#pragma unroll
            for (int ni = 0; ni < 4; ni++)
                bfv[ni] = *(const bf16x8*)&Bs[cur][(wn + ni * 16 + frow) * BK + off];
#pragma unroll
            for (int mi = 0; mi < 4; mi++)
#pragma unroll
                for (int ni = 0; ni < 4; ni++)
                    acc[mi][ni] = __builtin_amdgcn_mfma_f32_16x16x32_bf16(
                        af[mi], bfv[ni], acc[mi][ni], 0, 0, 0);
        }
        __builtin_amdgcn_sched_barrier(0);

        // cvt + swizzled ds_write of B(k+1); load latency was covered by
        // the compute above (T14 issue-early / write-late).
        if (kt + 1 < KSTEPS) {
#pragma unroll
            for (int i = 0; i < 4; i++) {
                u16x8 h;
                h[0] = f32_to_bf16_rne(p0[i].x);
                h[1] = f32_to_bf16_rne(p0[i].y);
                h[2] = f32_to_bf16_rne(p0[i].z);
                h[3] = f32_to_bf16_rne(p0[i].w);
                h[4] = f32_to_bf16_rne(p1[i].x);
                h[5] = f32_to_bf16_rne(p1[i].y);
                h[6] = f32_to_bf16_rne(p1[i].z);
                h[7] = f32_to_bf16_rne(p1[i].w);
                *(u16x8*)&Bs[cur ^ 1][bdst[i]] = h;
            }
        }
        __syncthreads();   // one barrier/K-step: tile k+1 ready, buf reuse safe
    }

    // Epilogue: C/D layout col = lane&15, row = (lane>>4)*4 + reg.
    unsigned short* ybase = ybuf + (size_t)(vexp >> 3) * T * D_MODEL;
    const int rbase = (lane >> 4) * 4;
    const int col   = lane & 15;
#pragma unroll
    for (int mi = 0; mi < 4; mi++) {
#pragma unroll
        for (int r = 0; r < 4; r++) {
            int lrow = wm + mi * 16 + rbase + r;
            if (m0 + lrow < n_e) {
                int   tk = tokS[lrow];
                float gv = gateS[lrow];
                unsigned short* yr = ybase + (size_t)tk * D_MODEL;
#pragma unroll
                for (int ni = 0; ni < 4; ni++) {
                    int c = n0 + wn + ni * 16 + col;
                    float val = gv * (acc[mi][ni][r] + be[e_w * D_MODEL + c]);
                    yr[c] = f32_to_bf16_rne(val);
                }
            }
        }
    }
}

// ---------------------------------------------------------------------------
// Combine: out[t][d] = ybuf[0][t][d] + ybuf[1][t][d]  (bf16 -> fp32 add)
// ---------------------------------------------------------------------------
__global__ __launch_bounds__(256) void combine_kernel(
    const unsigned short* __restrict__ y0,
    const unsigned short* __restrict__ y1,
    float* __restrict__ out, int n4)
{
    int i = blockIdx.x * 256 + threadIdx.x;
    if (i >= n4) return;
    ushort4 a = ((const ushort4*)y0)[i];
    ushort4 b = ((const ushort4*)y1)[i];
    float4 o;
    o.x = bf16_to_f32(a.x) + bf16_to_f32(b.x);
    o.y = bf16_to_f32(a.y) + bf16_to_f32(b.y);
    o.z = bf16_to_f32(a.z) + bf16_to_f32(b.z);
    o.w = bf16_to_f32(a.w) + bf16_to_f32(b.w);
    ((float4*)out)[i] = o;
}

extern "C" void kernel_launch(void* const* d_in, const int* in_sizes, int n_in,
                              void* d_out, int out_size, void* d_ws, size_t ws_size,
                              hipStream_t stream) {
    const float* x  = (const float*)d_in[0];
    const float* Wg = (const float*)d_in[1];
    const float* bg = (const float*)d_in[2];
    const float* We = (const float*)d_in[3];
    const float* be = (const float*)d_in[4];
    // top_k (d_in[5]) is fixed at 2 per the reference; hard-coded.

    const int T = in_sizes[0] / D_MODEL;   // 8192 tokens

    // workspace carve-up (no wbv anymore — conversion fused into moe_gemm)
    char* ws = (char*)d_ws;
    unsigned short* xb = (unsigned short*)ws;                       // T*D bf16
    size_t off = (size_t)T * D_MODEL * 2;
    int* counts = (int*)(ws + off);         off += 256;
    int* token_list = (int*)(ws + off);     off += (size_t)NBUCKET * T * 4;
    float* gate_list = (float*)(ws + off);  off += (size_t)NBUCKET * T * 4;
    unsigned short* ybuf = (unsigned short*)(ws + off);             // 2*T*D bf16
    off += (size_t)2 * T * D_MODEL * 2;

    hipMemsetAsync(counts, 0, 256, stream);

    gate_kernel<<<T / GATE_TOK, 512, 0, stream>>>(
        x, Wg, bg, T, counts, token_list, gate_list, xb);

    const int MT = (T + BM - 1) / BM;       // worst case: all tokens in one bucket
    moe_gemm<<<MT * NBUCKET * 8, 256, 0, stream>>>(
        xb, We, be, counts, token_list, gate_list, ybuf, T);

    int n4c = T * D_MODEL / 4;
    combine_kernel<<<(n4c + 255) / 256, 256, 0, stream>>>(
        ybuf, ybuf + (size_t)T * D_MODEL, (float*)d_out, n4c);
}

// Round 9
// 231.606 us; speedup vs baseline: 1.6825x; 1.1385x over previous
//
#include <hip/hip_runtime.h>
#include <hip/hip_bf16.h>
#include <stdint.h>

#define D_MODEL 1024
#define NUM_EXPERTS 8
#define NBUCKET 16            // 8 primary + 8 secondary virtual experts
#define BM 128
#define BN 128
#define BK 64
#define KSTEPS (D_MODEL / BK)   // 16
#define GATE_TOK 32           // tokens per gate block (256 gate blocks)
#define GATE_BLOCKS 256       // T / GATE_TOK
#define CONV_BLOCKS 2048      // NSEG / 512
#define NSEG (NUM_EXPERTS * KSTEPS * 1024 * 8)   // 1048576 16B-segments

typedef __bf16 bf16x8 __attribute__((ext_vector_type(8)));
typedef float f32x4 __attribute__((ext_vector_type(4)));
typedef unsigned short u16x8 __attribute__((ext_vector_type(8)));

__device__ __forceinline__ unsigned short f32_to_bf16_rne(float f) {
    union { float f; uint32_t u; } v;
    v.f = f;
    uint32_t u = v.u;
    u += 0x7FFFu + ((u >> 16) & 1u);   // round-to-nearest-even
    return (unsigned short)(u >> 16);
}

__device__ __forceinline__ float bf16_to_f32(unsigned short h) {
    union { uint32_t u; float f; } v;
    v.u = ((uint32_t)h) << 16;
    return v.f;
}

__device__ __forceinline__ void gload_lds16(const unsigned short* g, unsigned short* l) {
    __builtin_amdgcn_global_load_lds(
        (const __attribute__((address_space(1))) void*)g,
        (__attribute__((address_space(3))) void*)l,
        16, 0, 0);
}

// ---------------------------------------------------------------------------
// prep_kernel (512 threads, 34 KB LDS -> 4 blocks/CU = 32 waves = FULL
// occupancy for both branches; r2's merge failed at 256thr = 16-wave cap):
//   blocks [0, 256):        gate, 32 tokens each (r7-verified 512-thr body)
//   blocks [256, 256+2048): We fp32->bf16, LINEAR reads (src = g*8),
//                           128B-chunk writes of the blocked+swizzled image
//                           wbv[e][kt][n][seg^(n&7)][8] (byte-identical to
//                           the r3-verified convert output).
// ---------------------------------------------------------------------------
__global__ __launch_bounds__(512) void prep_kernel(
    const float* __restrict__ x, const float* __restrict__ Wg,
    const float* __restrict__ bg, const float* __restrict__ We, int T,
    int* __restrict__ counts, int* __restrict__ token_list,
    float* __restrict__ gate_list, unsigned short* __restrict__ xb,
    unsigned short* __restrict__ wbv)
{
    const int tid = threadIdx.x;

    if (blockIdx.x >= GATE_BLOCKS) {
        // ----------------- convert branch (pure BW, no LDS use) -----------
        int g = (blockIdx.x - GATE_BLOCKS) * 512 + tid;   // 0 .. NSEG-1
        int s   = g & 7;
        int kt  = (g >> 3) & (KSTEPS - 1);
        int n   = (g >> 7) & 1023;
        int e   = g >> 17;

        const float* sp = We + (size_t)g * 8;             // LINEAR 32B/thread
        float4 a = ((const float4*)sp)[0];
        float4 b = ((const float4*)sp)[1];
        u16x8 o;
        o[0] = f32_to_bf16_rne(a.x);
        o[1] = f32_to_bf16_rne(a.y);
        o[2] = f32_to_bf16_rne(a.z);
        o[3] = f32_to_bf16_rne(a.w);
        o[4] = f32_to_bf16_rne(b.x);
        o[5] = f32_to_bf16_rne(b.y);
        o[6] = f32_to_bf16_rne(b.z);
        o[7] = f32_to_bf16_rne(b.w);

        int ss = s ^ (n & 7);
        unsigned short* dp =
            wbv + (((size_t)(e * KSTEPS + kt) * 1024 + n) * BK) + ss * 8;
        *(u16x8*)dp = o;
        return;
    }

    // ----------------- gate branch (r7-verified 512-thread body) ----------
    const int lane = tid & 63;
    const int wave = tid >> 6;            // 0..7
    const int tokBase = blockIdx.x * GATE_TOK;

    __shared__ float4 WgS[NUM_EXPERTS * 256];   // 32 KB
    __shared__ double logitS[GATE_TOK][NUM_EXPERTS];
    __shared__ int cntS[NBUCKET];
    __shared__ int baseS[NBUCKET];

    if (tid < NBUCKET) cntS[tid] = 0;
#pragma unroll
    for (int i = 0; i < 4; i++)
        WgS[i * 512 + tid] = ((const float4*)Wg)[i * 512 + tid];
    __syncthreads();

    // Each of 8 waves handles GATE_TOK/8 = 4 tokens.
    for (int tt = 0; tt < GATE_TOK / 8; tt++) {
        const int lt = wave * (GATE_TOK / 8) + tt;
        const int token = tokBase + lt;
        const float4* xr4 = (const float4*)(x + (size_t)token * D_MODEL);
        ushort4* xbr4 = (ushort4*)(xb + (size_t)token * D_MODEL);

        float4 xv[4];
#pragma unroll
        for (int q = 0; q < 4; q++) {
            float4 f = xr4[q * 64 + lane];
            xv[q] = f;
            ushort4 o;
            o.x = f32_to_bf16_rne(f.x);
            o.y = f32_to_bf16_rne(f.y);
            o.z = f32_to_bf16_rne(f.z);
            o.w = f32_to_bf16_rne(f.w);
            xbr4[q * 64 + lane] = o;
        }

        double acc[NUM_EXPERTS];
#pragma unroll
        for (int e = 0; e < NUM_EXPERTS; e++) {
            double a = 0.0;
#pragma unroll
            for (int q = 0; q < 4; q++) {
                float4 w = WgS[e * 256 + q * 64 + lane];
                a += (double)xv[q].x * (double)w.x;
                a += (double)xv[q].y * (double)w.y;
                a += (double)xv[q].z * (double)w.z;
                a += (double)xv[q].w * (double)w.w;
            }
            acc[e] = a;
        }
#pragma unroll
        for (int e = 0; e < NUM_EXPERTS; e++) {
            double a = acc[e];
            for (int off = 32; off > 0; off >>= 1) a += __shfl_xor(a, off, 64);
            acc[e] = a;
        }
        if (lane == 0) {
#pragma unroll
            for (int e = 0; e < NUM_EXPERTS; e++)
                logitS[lt][e] = acc[e] + (double)bg[e];
        }
    }
    __syncthreads();

    int i1 = 0, i2 = 0, o1 = 0, o2 = 0;
    double v1d = 0.0, v2d = 0.0;
    const int token2 = tokBase + tid;
    if (tid < GATE_TOK) {
        double lg[NUM_EXPERTS];
#pragma unroll
        for (int e = 0; e < NUM_EXPERTS; e++) lg[e] = logitS[tid][e];
        i1 = 0;
#pragma unroll
        for (int e = 1; e < NUM_EXPERTS; e++) if (lg[e] > lg[i1]) i1 = e;
        i2 = (i1 == 0) ? 1 : 0;
#pragma unroll
        for (int e = 0; e < NUM_EXPERTS; e++)
            if (e != i1 && lg[e] > lg[i2]) i2 = e;
        double m = lg[i1], den = 0.0;
#pragma unroll
        for (int e = 0; e < NUM_EXPERTS; e++) den += exp(lg[e] - m);
        v1d = exp(lg[i1] - m) / den;
        v2d = exp(lg[i2] - m) / den;
        o1 = atomicAdd(&cntS[i1], 1);          // primary bucket e
        o2 = atomicAdd(&cntS[8 + i2], 1);      // secondary bucket 8+e
    }
    __syncthreads();
    if (tid < NBUCKET) baseS[tid] = atomicAdd(&counts[tid], cntS[tid]);
    __syncthreads();
    if (tid < GATE_TOK) {
        int p1 = i1 * T + baseS[i1] + o1;
        token_list[p1] = token2;
        gate_list[p1]  = (float)v1d;
        int p2 = (8 + i2) * T + baseS[8 + i2] + o2;
        token_list[p2] = token2;
        gate_list[p2]  = (float)v2d;
    }
}

// ---------------------------------------------------------------------------
// Per-bucket gathered GEMM: r3-verified layout/swizzle/counted-vmcnt sync,
// now at 512 THREADS (8 waves) per block. Same 128x128 tile, same LDS image.
// At 256thr the kernel ran 8 waves/CU (2/SIMD) -- no latency hiding, MfmaUtil
// 21%. 512thr -> 16 waves/CU (4/SIMD). Wave owns a 64x32 sub-tile:
// wm=(wave>>2)*64, wn=(wave&3)*32; acc[4][2]; 16 MFMA/K-step/wave.
// Staging: 2 A + 2 B 16B-loads per thread per step -> s_waitcnt vmcnt(4).
// ---------------------------------------------------------------------------
__global__ __launch_bounds__(512) void moe_gemm(
    const unsigned short* __restrict__ xb,   // [T][1024] bf16
    const unsigned short* __restrict__ wb,   // [E][16][1024][64] bf16, swizzled
    const float* __restrict__ be,            // [E][1024]
    const int* __restrict__ counts,          // [16]
    const int* __restrict__ token_list,      // [16][T]
    const float* __restrict__ gate_list,     // [16][T]
    unsigned short* __restrict__ ybuf,       // [2][T][1024] bf16
    int T)
{
    const int bid = blockIdx.x;
    const int nt = bid & 7;
    const int rest = bid >> 3;
    const int vexp = rest & (NBUCKET - 1);
    const int mt = rest >> 4;
    const int e_w = vexp & 7;

    const int n_e = counts[vexp];
    const int m0 = mt * BM;
    if (m0 >= n_e) return;
    const int n0 = nt * BN;
    const int tid = threadIdx.x;

    __shared__ __align__(16) unsigned short As[2][BM * BK];   // 2 x 16 KB
    __shared__ __align__(16) unsigned short Bs[2][BN * BK];   // 2 x 16 KB
    __shared__ int   tokS[BM];
    __shared__ float gateS[BM];

    if (tid < BM) {
        int r = m0 + tid;
        int tk = 0; float gv = 0.f;
        if (r < n_e) {
            tk = token_list[vexp * T + r];
            gv = gate_list[vexp * T + r];
        }
        tokS[tid]  = tk;
        gateS[tid] = gv;
    }
    __syncthreads();

    // A staging sources: per-token gather, XOR swizzle on the 16B segment
    // index applied on the SOURCE (LDS dest stays wave-linear).
    const unsigned short* asrc[2];
#pragma unroll
    for (int i = 0; i < 2; i++) {
        int flat = i * 512 + tid;
        int r = flat >> 3, seg = flat & 7;
        int ss = seg ^ (r & 7);
        asrc[i] = xb + (size_t)tokS[r] * D_MODEL + ss * 8;
    }
    // B staging source: fully linear within each 16 KB per-K-step tile.
    const unsigned short* bsrc =
        wb + (size_t)e_w * (KSTEPS * 1024 * BK) + (size_t)n0 * BK;

    const int wave = tid >> 6, lane = tid & 63;
    const int wm = (wave >> 2) * 64, wn = (wave & 3) * 32;
    const int frow = lane & 15;
    const int qq = lane >> 4;
    const int sw8 = frow & 7;

    f32x4 acc[4][2];
#pragma unroll
    for (int mi = 0; mi < 4; mi++)
#pragma unroll
        for (int ni = 0; ni < 2; ni++)
            acc[mi][ni] = (f32x4){0.f, 0.f, 0.f, 0.f};

    // Prologue: stage K-tile 0 into buffer 0 (4 vm ops; waited in-loop).
#pragma unroll
    for (int i = 0; i < 2; i++) {
        int flat = i * 512 + tid;
        gload_lds16(asrc[i], &As[0][flat * 8]);
        gload_lds16(bsrc + flat * 8, &Bs[0][flat * 8]);
    }

#pragma unroll 2
    for (int kt = 0; kt < KSTEPS; kt++) {
        const int cur = kt & 1;
        // Prefetch next K-tile into the other buffer; its loads stay in
        // flight across both barriers (counted wait below, never vmcnt(0)).
        if (kt + 1 < KSTEPS) {
#pragma unroll
            for (int i = 0; i < 2; i++) {
                int flat = i * 512 + tid;
                gload_lds16(asrc[i] + (kt + 1) * BK, &As[cur ^ 1][flat * 8]);
                gload_lds16(bsrc + (size_t)(kt + 1) * (1024 * BK) + flat * 8,
                            &Bs[cur ^ 1][flat * 8]);
            }
            asm volatile("s_waitcnt vmcnt(4)" ::: "memory");  // tile k done
        } else {
            asm volatile("s_waitcnt vmcnt(0)" ::: "memory");  // tail
        }
        __builtin_amdgcn_sched_barrier(0);
        __builtin_amdgcn_s_barrier();          // all waves: tile k in LDS
        __builtin_amdgcn_sched_barrier(0);

#pragma unroll
        for (int ks = 0; ks < 2; ks++) {
            const int off = ((ks * 4 + qq) ^ sw8) * 8;   // swizzled k-offset
            bf16x8 af[4], bfv[2];
#pragma unroll
            for (int mi = 0; mi < 4; mi++)
                af[mi] = *(const bf16x8*)&As[cur][(wm + mi * 16 + frow) * BK + off];
#pragma unroll
            for (int ni = 0; ni < 2; ni++)
                bfv[ni] = *(const bf16x8*)&Bs[cur][(wn + ni * 16 + frow) * BK + off];
#pragma unroll
            for (int mi = 0; mi < 4; mi++)
#pragma unroll
                for (int ni = 0; ni < 2; ni++)
                    acc[mi][ni] = __builtin_amdgcn_mfma_f32_16x16x32_bf16(
                        af[mi], bfv[ni], acc[mi][ni], 0, 0, 0);
        }
        __builtin_amdgcn_sched_barrier(0);
        __builtin_amdgcn_s_barrier();          // buf[cur] free for stage(k+2)
        __builtin_amdgcn_sched_barrier(0);
    }

    // Epilogue: C/D layout col = lane&15, row = (lane>>4)*4 + reg.
    unsigned short* ybase = ybuf + (size_t)(vexp >> 3) * T * D_MODEL;
    const int rbase = (lane >> 4) * 4;
    const int col   = lane & 15;
#pragma unroll
    for (int mi = 0; mi < 4; mi++) {
#pragma unroll
        for (int r = 0; r < 4; r++) {
            int lrow = wm + mi * 16 + rbase + r;
            if (m0 + lrow < n_e) {
                int   tk = tokS[lrow];
                float gv = gateS[lrow];
                unsigned short* yr = ybase + (size_t)tk * D_MODEL;
#pragma unroll
                for (int ni = 0; ni < 2; ni++) {
                    int c = n0 + wn + ni * 16 + col;
                    float val = gv * (acc[mi][ni][r] + be[e_w * D_MODEL + c]);
                    yr[c] = f32_to_bf16_rne(val);
                }
            }
        }
    }
}

// ---------------------------------------------------------------------------
// Combine: out[t][d] = ybuf[0][t][d] + ybuf[1][t][d]  (bf16 -> fp32 add)
// ---------------------------------------------------------------------------
__global__ __launch_bounds__(256) void combine_kernel(
    const unsigned short* __restrict__ y0,
    const unsigned short* __restrict__ y1,
    float* __restrict__ out, int n4)
{
    int i = blockIdx.x * 256 + threadIdx.x;
    if (i >= n4) return;
    ushort4 a = ((const ushort4*)y0)[i];
    ushort4 b = ((const ushort4*)y1)[i];
    float4 o;
    o.x = bf16_to_f32(a.x) + bf16_to_f32(b.x);
    o.y = bf16_to_f32(a.y) + bf16_to_f32(b.y);
    o.z = bf16_to_f32(a.z) + bf16_to_f32(b.z);
    o.w = bf16_to_f32(a.w) + bf16_to_f32(b.w);
    ((float4*)out)[i] = o;
}

extern "C" void kernel_launch(void* const* d_in, const int* in_sizes, int n_in,
                              void* d_out, int out_size, void* d_ws, size_t ws_size,
                              hipStream_t stream) {
    const float* x  = (const float*)d_in[0];
    const float* Wg = (const float*)d_in[1];
    const float* bg = (const float*)d_in[2];
    const float* We = (const float*)d_in[3];
    const float* be = (const float*)d_in[4];
    // top_k (d_in[5]) is fixed at 2 per the reference; hard-coded.

    const int T = in_sizes[0] / D_MODEL;   // 8192 tokens

    // workspace carve-up (~68 MB total)
    char* ws = (char*)d_ws;
    unsigned short* xb = (unsigned short*)ws;                       // T*D bf16
    size_t off = (size_t)T * D_MODEL * 2;
    unsigned short* wbv = (unsigned short*)(ws + off);              // E*D*D bf16
    off += (size_t)NUM_EXPERTS * D_MODEL * D_MODEL * 2;
    int* counts = (int*)(ws + off);         off += 256;
    int* token_list = (int*)(ws + off);     off += (size_t)NBUCKET * T * 4;
    float* gate_list = (float*)(ws + off);  off += (size_t)NBUCKET * T * 4;
    unsigned short* ybuf = (unsigned short*)(ws + off);             // 2*T*D bf16
    off += (size_t)2 * T * D_MODEL * 2;

    hipMemsetAsync(counts, 0, 256, stream);

    prep_kernel<<<GATE_BLOCKS + CONV_BLOCKS, 512, 0, stream>>>(
        x, Wg, bg, We, T, counts, token_list, gate_list, xb, wbv);

    const int MT = (T + BM - 1) / BM;       // worst case: all tokens in one bucket
    moe_gemm<<<MT * NBUCKET * 8, 512, 0, stream>>>(
        xb, wbv, be, counts, token_list, gate_list, ybuf, T);

    int n4c = T * D_MODEL / 4;
    combine_kernel<<<(n4c + 255) / 256, 256, 0, stream>>>(
        ybuf, ybuf + (size_t)T * D_MODEL, (float*)d_out, n4c);
}

// Round 10
// 200.204 us; speedup vs baseline: 1.9464x; 1.1569x over previous
//
#include <hip/hip_runtime.h>
#include <hip/hip_bf16.h>
#include <stdint.h>

#define D_MODEL 1024
#define NUM_EXPERTS 8
#define NBUCKET 16            // 8 primary + 8 secondary virtual experts
#define BM 128
#define BN 128
#define BK 64
#define KSTEPS (D_MODEL / BK)   // 16
#define GATE_TOK 8            // tokens per gate block: 1024 blocks, 256 thr
#define NSEG (NUM_EXPERTS * KSTEPS * 1024 * 8)   // 1048576 16B-segments

typedef __bf16 bf16x8 __attribute__((ext_vector_type(8)));
typedef float f32x4 __attribute__((ext_vector_type(4)));
typedef unsigned short u16x8 __attribute__((ext_vector_type(8)));

__device__ __forceinline__ unsigned short f32_to_bf16_rne(float f) {
    union { float f; uint32_t u; } v;
    v.f = f;
    uint32_t u = v.u;
    u += 0x7FFFu + ((u >> 16) & 1u);   // round-to-nearest-even
    return (unsigned short)(u >> 16);
}

__device__ __forceinline__ float bf16_to_f32(unsigned short h) {
    union { uint32_t u; float f; } v;
    v.u = ((uint32_t)h) << 16;
    return v.f;
}

__device__ __forceinline__ void gload_lds16(const unsigned short* g, unsigned short* l) {
    __builtin_amdgcn_global_load_lds(
        (const __attribute__((address_space(1))) void*)g,
        (__attribute__((address_space(3))) void*)l,
        16, 0, 0);
}

// ---------------------------------------------------------------------------
// Gate kernel v4: LDS transpose-reduce replaces the 96-dependent-shuffle
// fp64 butterfly (r9 PMC: gate was ~55+ us, latency-bound, VALUBusy 6%).
//  - No Wg LDS staging (32 KB L2-hot; read float4 per use).
//  - Per wave (2 tokens): 8 fp64 partials/lane -> wave-private LDS
//    red[wave][e][65] (pad 65 -> b64-baseline banking), lane (e,g) sums 8
//    consecutive + 3-level shfl_xor. 16 batched DS ops + 6 shuffles/token.
//  - fp64 math kept: only reduction ORDER changes (~1e-16 perturbation);
//    strict top-2 (lower index wins ties) and fp64 softmax identical.
//  - 1024 blocks x 256 thr, ~17.4 KB LDS -> high occupancy, no stragglers.
// ---------------------------------------------------------------------------
__global__ __launch_bounds__(256) void gate_kernel(
    const float* __restrict__ x, const float* __restrict__ Wg,
    const float* __restrict__ bg, int T,
    int* __restrict__ counts, int* __restrict__ token_list,
    float* __restrict__ gate_list, unsigned short* __restrict__ xb)
{
    const int tid  = threadIdx.x;
    const int lane = tid & 63;
    const int wave = tid >> 6;            // 0..3
    const int tokBase = blockIdx.x * GATE_TOK;

    __shared__ double red[4][NUM_EXPERTS][65];   // 16.6 KB, wave-private rows
    __shared__ double logitS[GATE_TOK][NUM_EXPERTS];
    __shared__ int cntS[NBUCKET];
    __shared__ int baseS[NBUCKET];

    if (tid < NBUCKET) cntS[tid] = 0;

    const float4* Wg4 = (const float4*)Wg;

    // Load 2 tokens per wave; fuse x fp32->bf16 (RNE) conversion.
    float4 xv[2][4];
#pragma unroll
    for (int t = 0; t < 2; t++) {
        const int token = tokBase + wave * 2 + t;
        const float4* xr4 = (const float4*)(x + (size_t)token * D_MODEL);
        ushort4* xbr4 = (ushort4*)(xb + (size_t)token * D_MODEL);
#pragma unroll
        for (int q = 0; q < 4; q++) {
            float4 f = xr4[q * 64 + lane];
            xv[t][q] = f;
            ushort4 o;
            o.x = f32_to_bf16_rne(f.x);
            o.y = f32_to_bf16_rne(f.y);
            o.z = f32_to_bf16_rne(f.z);
            o.w = f32_to_bf16_rne(f.w);
            xbr4[q * 64 + lane] = o;
        }
    }

    // fp64 partials: Wg loaded once per (e,q), reused across both tokens.
    double acc[2][NUM_EXPERTS];
#pragma unroll
    for (int t = 0; t < 2; t++)
#pragma unroll
        for (int e = 0; e < NUM_EXPERTS; e++) acc[t][e] = 0.0;
#pragma unroll
    for (int e = 0; e < NUM_EXPERTS; e++) {
#pragma unroll
        for (int q = 0; q < 4; q++) {
            float4 w = Wg4[e * 256 + q * 64 + lane];
#pragma unroll
            for (int t = 0; t < 2; t++) {
                acc[t][e] += (double)xv[t][q].x * (double)w.x;
                acc[t][e] += (double)xv[t][q].y * (double)w.y;
                acc[t][e] += (double)xv[t][q].z * (double)w.z;
                acc[t][e] += (double)xv[t][q].w * (double)w.w;
            }
        }
    }

    // LDS transpose-reduce (wave-private region: no __syncthreads needed).
    const int e2 = lane >> 3, g = lane & 7;
#pragma unroll
    for (int t = 0; t < 2; t++) {
#pragma unroll
        for (int e = 0; e < NUM_EXPERTS; e++)
            red[wave][e][lane] = acc[t][e];
        double s = 0.0;
#pragma unroll
        for (int j = 0; j < 8; j++)
            s += red[wave][e2][g * 8 + j];
        s += __shfl_xor(s, 1, 64);
        s += __shfl_xor(s, 2, 64);
        s += __shfl_xor(s, 4, 64);
        if (g == 0)
            logitS[wave * 2 + t][e2] = s + (double)bg[e2];
    }
    __syncthreads();

    // Phase 2: one thread per token — strict top-2 (lower index wins ties,
    // matches lax.top_k) + fp64 softmax + block-aggregated bucket append.
    int i1 = 0, i2 = 0, o1 = 0, o2 = 0;
    double v1d = 0.0, v2d = 0.0;
    const int token2 = tokBase + tid;
    if (tid < GATE_TOK) {
        double lg[NUM_EXPERTS];
#pragma unroll
        for (int e = 0; e < NUM_EXPERTS; e++) lg[e] = logitS[tid][e];
        i1 = 0;
#pragma unroll
        for (int e = 1; e < NUM_EXPERTS; e++) if (lg[e] > lg[i1]) i1 = e;
        i2 = (i1 == 0) ? 1 : 0;
#pragma unroll
        for (int e = 0; e < NUM_EXPERTS; e++)
            if (e != i1 && lg[e] > lg[i2]) i2 = e;
        double m = lg[i1], den = 0.0;
#pragma unroll
        for (int e = 0; e < NUM_EXPERTS; e++) den += exp(lg[e] - m);
        v1d = exp(lg[i1] - m) / den;
        v2d = exp(lg[i2] - m) / den;
        o1 = atomicAdd(&cntS[i1], 1);          // primary bucket e
        o2 = atomicAdd(&cntS[8 + i2], 1);      // secondary bucket 8+e
    }
    __syncthreads();
    if (tid < NBUCKET) baseS[tid] = atomicAdd(&counts[tid], cntS[tid]);
    __syncthreads();
    if (tid < GATE_TOK) {
        int p1 = i1 * T + baseS[i1] + o1;
        token_list[p1] = token2;
        gate_list[p1]  = (float)v1d;
        int p2 = (8 + i2) * T + baseS[8 + i2] + o2;
        token_list[p2] = token2;
        gate_list[p2]  = (float)v2d;
    }
}

// ---------------------------------------------------------------------------
// fp32 -> bf16 converter for We, standalone, LINEAR reads (src = g*8 floats).
// Output layout: wbv[e][kt][n][seg^(n&7)][8] (byte-identical image to the
// r3-verified pre-swizzled blocked layout; each (e,kt,n) 128B row is fully
// covered by 8 consecutive threads).
// ---------------------------------------------------------------------------
__global__ __launch_bounds__(256) void convert_kernel(
    const float* __restrict__ src, unsigned short* __restrict__ dst)
{
    int g = blockIdx.x * 256 + threadIdx.x;   // 0 .. NSEG-1
    int s   = g & 7;
    int kt  = (g >> 3) & (KSTEPS - 1);
    int n   = (g >> 7) & 1023;
    int e   = g >> 17;

    const float* sp = src + (size_t)g * 8;    // linear 32B/thread
    float4 a = ((const float4*)sp)[0];
    float4 b = ((const float4*)sp)[1];
    u16x8 o;
    o[0] = f32_to_bf16_rne(a.x);
    o[1] = f32_to_bf16_rne(a.y);
    o[2] = f32_to_bf16_rne(a.z);
    o[3] = f32_to_bf16_rne(a.w);
    o[4] = f32_to_bf16_rne(b.x);
    o[5] = f32_to_bf16_rne(b.y);
    o[6] = f32_to_bf16_rne(b.z);
    o[7] = f32_to_bf16_rne(b.w);

    int ss = s ^ (n & 7);
    unsigned short* dp =
        dst + (((size_t)(e * KSTEPS + kt) * 1024 + n) * BK) + ss * 8;
    *(u16x8*)dp = o;
}

// ---------------------------------------------------------------------------
// Per-bucket gathered GEMM (r9 512-thread version, unchanged — control):
// r3-verified layout/swizzle + counted-vmcnt double-buffer; 8 waves/block,
// wave owns 64x32 sub-tile; stage = 2A+2B 16B loads/thread -> vmcnt(4).
// ---------------------------------------------------------------------------
__global__ __launch_bounds__(512) void moe_gemm(
    const unsigned short* __restrict__ xb,   // [T][1024] bf16
    const unsigned short* __restrict__ wb,   // [E][16][1024][64] bf16, swizzled
    const float* __restrict__ be,            // [E][1024]
    const int* __restrict__ counts,          // [16]
    const int* __restrict__ token_list,      // [16][T]
    const float* __restrict__ gate_list,     // [16][T]
    unsigned short* __restrict__ ybuf,       // [2][T][1024] bf16
    int T)
{
    const int bid = blockIdx.x;
    const int nt = bid & 7;
    const int rest = bid >> 3;
    const int vexp = rest & (NBUCKET - 1);
    const int mt = rest >> 4;
    const int e_w = vexp & 7;

    const int n_e = counts[vexp];
    const int m0 = mt * BM;
    if (m0 >= n_e) return;
    const int n0 = nt * BN;
    const int tid = threadIdx.x;

    __shared__ __align__(16) unsigned short As[2][BM * BK];   // 2 x 16 KB
    __shared__ __align__(16) unsigned short Bs[2][BN * BK];   // 2 x 16 KB
    __shared__ int   tokS[BM];
    __shared__ float gateS[BM];

    if (tid < BM) {
        int r = m0 + tid;
        int tk = 0; float gv = 0.f;
        if (r < n_e) {
            tk = token_list[vexp * T + r];
            gv = gate_list[vexp * T + r];
        }
        tokS[tid]  = tk;
        gateS[tid] = gv;
    }
    __syncthreads();

    const unsigned short* asrc[2];
#pragma unroll
    for (int i = 0; i < 2; i++) {
        int flat = i * 512 + tid;
        int r = flat >> 3, seg = flat & 7;
        int ss = seg ^ (r & 7);
        asrc[i] = xb + (size_t)tokS[r] * D_MODEL + ss * 8;
    }
    const unsigned short* bsrc =
        wb + (size_t)e_w * (KSTEPS * 1024 * BK) + (size_t)n0 * BK;

    const int wave = tid >> 6, lane = tid & 63;
    const int wm = (wave >> 2) * 64, wn = (wave & 3) * 32;
    const int frow = lane & 15;
    const int qq = lane >> 4;
    const int sw8 = frow & 7;

    f32x4 acc[4][2];
#pragma unroll
    for (int mi = 0; mi < 4; mi++)
#pragma unroll
        for (int ni = 0; ni < 2; ni++)
            acc[mi][ni] = (f32x4){0.f, 0.f, 0.f, 0.f};

    // Prologue: stage K-tile 0 into buffer 0 (4 vm ops; waited in-loop).
#pragma unroll
    for (int i = 0; i < 2; i++) {
        int flat = i * 512 + tid;
        gload_lds16(asrc[i], &As[0][flat * 8]);
        gload_lds16(bsrc + flat * 8, &Bs[0][flat * 8]);
    }

#pragma unroll 2
    for (int kt = 0; kt < KSTEPS; kt++) {
        const int cur = kt & 1;
        if (kt + 1 < KSTEPS) {
#pragma unroll
            for (int i = 0; i < 2; i++) {
                int flat = i * 512 + tid;
                gload_lds16(asrc[i] + (kt + 1) * BK, &As[cur ^ 1][flat * 8]);
                gload_lds16(bsrc + (size_t)(kt + 1) * (1024 * BK) + flat * 8,
                            &Bs[cur ^ 1][flat * 8]);
            }
            asm volatile("s_waitcnt vmcnt(4)" ::: "memory");  // tile k done
        } else {
            asm volatile("s_waitcnt vmcnt(0)" ::: "memory");  // tail
        }
        __builtin_amdgcn_sched_barrier(0);
        __builtin_amdgcn_s_barrier();          // all waves: tile k in LDS
        __builtin_amdgcn_sched_barrier(0);

#pragma unroll
        for (int ks = 0; ks < 2; ks++) {
            const int off = ((ks * 4 + qq) ^ sw8) * 8;   // swizzled k-offset
            bf16x8 af[4], bfv[2];
#pragma unroll
            for (int mi = 0; mi < 4; mi++)
                af[mi] = *(const bf16x8*)&As[cur][(wm + mi * 16 + frow) * BK + off];
#pragma unroll
            for (int ni = 0; ni < 2; ni++)
                bfv[ni] = *(const bf16x8*)&Bs[cur][(wn + ni * 16 + frow) * BK + off];
#pragma unroll
            for (int mi = 0; mi < 4; mi++)
#pragma unroll
                for (int ni = 0; ni < 2; ni++)
                    acc[mi][ni] = __builtin_amdgcn_mfma_f32_16x16x32_bf16(
                        af[mi], bfv[ni], acc[mi][ni], 0, 0, 0);
        }
        __builtin_amdgcn_sched_barrier(0);
        __builtin_amdgcn_s_barrier();          // buf[cur] free for stage(k+2)
        __builtin_amdgcn_sched_barrier(0);
    }

    // Epilogue: C/D layout col = lane&15, row = (lane>>4)*4 + reg.
    unsigned short* ybase = ybuf + (size_t)(vexp >> 3) * T * D_MODEL;
    const int rbase = (lane >> 4) * 4;
    const int col   = lane & 15;
#pragma unroll
    for (int mi = 0; mi < 4; mi++) {
#pragma unroll
        for (int r = 0; r < 4; r++) {
            int lrow = wm + mi * 16 + rbase + r;
            if (m0 + lrow < n_e) {
                int   tk = tokS[lrow];
                float gv = gateS[lrow];
                unsigned short* yr = ybase + (size_t)tk * D_MODEL;
#pragma unroll
                for (int ni = 0; ni < 2; ni++) {
                    int c = n0 + wn + ni * 16 + col;
                    float val = gv * (acc[mi][ni][r] + be[e_w * D_MODEL + c]);
                    yr[c] = f32_to_bf16_rne(val);
                }
            }
        }
    }
}

// ---------------------------------------------------------------------------
// Combine: out[t][d] = ybuf[0][t][d] + ybuf[1][t][d]  (bf16 -> fp32 add)
// ---------------------------------------------------------------------------
__global__ __launch_bounds__(256) void combine_kernel(
    const unsigned short* __restrict__ y0,
    const unsigned short* __restrict__ y1,
    float* __restrict__ out, int n4)
{
    int i = blockIdx.x * 256 + threadIdx.x;
    if (i >= n4) return;
    ushort4 a = ((const ushort4*)y0)[i];
    ushort4 b = ((const ushort4*)y1)[i];
    float4 o;
    o.x = bf16_to_f32(a.x) + bf16_to_f32(b.x);
    o.y = bf16_to_f32(a.y) + bf16_to_f32(b.y);
    o.z = bf16_to_f32(a.z) + bf16_to_f32(b.z);
    o.w = bf16_to_f32(a.w) + bf16_to_f32(b.w);
    ((float4*)out)[i] = o;
}

extern "C" void kernel_launch(void* const* d_in, const int* in_sizes, int n_in,
                              void* d_out, int out_size, void* d_ws, size_t ws_size,
                              hipStream_t stream) {
    const float* x  = (const float*)d_in[0];
    const float* Wg = (const float*)d_in[1];
    const float* bg = (const float*)d_in[2];
    const float* We = (const float*)d_in[3];
    const float* be = (const float*)d_in[4];
    // top_k (d_in[5]) is fixed at 2 per the reference; hard-coded.

    const int T = in_sizes[0] / D_MODEL;   // 8192 tokens

    // workspace carve-up (~68 MB total)
    char* ws = (char*)d_ws;
    unsigned short* xb = (unsigned short*)ws;                       // T*D bf16
    size_t off = (size_t)T * D_MODEL * 2;
    unsigned short* wbv = (unsigned short*)(ws + off);              // E*D*D bf16
    off += (size_t)NUM_EXPERTS * D_MODEL * D_MODEL * 2;
    int* counts = (int*)(ws + off);         off += 256;
    int* token_list = (int*)(ws + off);     off += (size_t)NBUCKET * T * 4;
    float* gate_list = (float*)(ws + off);  off += (size_t)NBUCKET * T * 4;
    unsigned short* ybuf = (unsigned short*)(ws + off);             // 2*T*D bf16
    off += (size_t)2 * T * D_MODEL * 2;

    hipMemsetAsync(counts, 0, 256, stream);

    convert_kernel<<<NSEG / 256, 256, 0, stream>>>(We, wbv);

    gate_kernel<<<T / GATE_TOK, 256, 0, stream>>>(
        x, Wg, bg, T, counts, token_list, gate_list, xb);

    const int MT = (T + BM - 1) / BM;       // worst case: all tokens in one bucket
    moe_gemm<<<MT * NBUCKET * 8, 512, 0, stream>>>(
        xb, wbv, be, counts, token_list, gate_list, ybuf, T);

    int n4c = T * D_MODEL / 4;
    combine_kernel<<<(n4c + 255) / 256, 256, 0, stream>>>(
        ybuf, ybuf + (size_t)T * D_MODEL, (float*)d_out, n4c);
}